// Round 14
// baseline (414.375 us; speedup 1.0000x reference)
//
#include <hip/hip_runtime.h>

typedef _Float16 f16;
typedef _Float16 f16x8 __attribute__((ext_vector_type(8)));
typedef _Float16 f16x4 __attribute__((ext_vector_type(4)));
typedef __fp16 h16x2 __attribute__((ext_vector_type(2)));
typedef float f32x4 __attribute__((ext_vector_type(4)));

constexpr int HDIM = 256, WDIM = 256, C_ = 192, NH_ = 6;
constexpr float SCALE = 0.17677669529663687f;  // 32^-0.5

// workspace layout (bytes)
constexpr size_t OFF_WQ   = 0;         // packed qkv weights: 13824 frags * 8 f16 = 221184 B
constexpr size_t OFF_WP   = 221184;    // packed proj weights: 4608 frags * 8 f16 = 73728 B
constexpr size_t OFF_BIAS = 294912;    // packed bias (f16): 6144 frags * 4 f16 = 49152 B
constexpr size_t OFF_ATT  = 344064;    // att f16 [4096*64][192] = 100663296 B

__global__ __launch_bounds__(256) void prep_kernel(const float* __restrict__ qkv_w,
                                                   const float* __restrict__ proj_w,
                                                   const float* __restrict__ rpb,
                                                   f16* __restrict__ wqp, f16* __restrict__ wpp,
                                                   f16* __restrict__ biasp) {
    int i = blockIdx.x * 256 + threadIdx.x;
    if (i < 13824) {                       // qkv frags: entry = ((w*3+c)*2+dt)*6+ks
        int lane = i & 63, rest = i >> 6;
        int ks = rest % 6; rest /= 6;
        int dt = rest & 1; rest >>= 1;
        int c = rest % 3, w = rest / 3;
        int l15 = lane & 15, lg = lane >> 4;
        int row = c * 192 + w * 32 + dt * 16 + l15;
        int col = ks * 32 + lg * 8;
#pragma unroll
        for (int j = 0; j < 8; ++j) wqp[(size_t)i * 8 + j] = (f16)qkv_w[row * 192 + col + j];
    } else if (i < 18432) {                // proj frags: entry = (w*2+nt)*6+ks
        int g = i - 13824;
        int lane = g & 63, rest = g >> 6;
        int ks = rest % 6; rest /= 6;
        int nt = rest & 1, w = rest >> 1;
        int l15 = lane & 15, lg = lane >> 4;
        int row = w * 32 + nt * 16 + l15;
        int col = ks * 32 + lg * 8;
#pragma unroll
        for (int j = 0; j < 8; ++j) wpp[(size_t)g * 8 + j] = (f16)proj_w[row * 192 + col + j];
    } else if (i < 24576) {                // bias frags (f16): entry = (h*4+qt)*4+kt
        int g = i - 18432;
        int lane = g & 63;
        int kt = (g >> 6) & 3, qt = (g >> 8) & 3, h = g >> 10;
        int q = qt * 16 + (lane & 15);
#pragma unroll
        for (int j = 0; j < 4; ++j) {
            int k = kt * 16 + (lane >> 4) * 4 + j;
            int dy = (q >> 3) - (k >> 3) + 7;
            int dx = (q & 7) - (k & 7) + 7;
            biasp[(size_t)g * 4 + j] = (f16)rpb[(dy * 15 + dx) * NH_ + h];
        }
    }
}

// ---- K1: one wave (64-thread block) = one (window, head). No LDS, no barriers.
// xt fragments loaded directly from global (window data is L2/L3-hot across the
// 6 head-waves). QKV swapped-operand q,k; in-register attention; O^T -> att.
__global__ __launch_bounds__(64, 2) void qkv_attn_kernel(const float* __restrict__ x,
                                                         const f16* __restrict__ wqp,
                                                         const f16* __restrict__ biasp,
                                                         f16* __restrict__ att) {
    const int bid = blockIdx.x;
    const int win = bid / 6;
    const int w = bid - win * 6;
    const int lane = threadIdx.x;
    const int l15 = lane & 15, lg = lane >> 4;
    const int b = win >> 10, wy = (win >> 5) & 31, wx = win & 31;

    const f16x8* wqb   = (const f16x8*)wqp + (size_t)w * 36 * 64 + lane;
    const f16x4* bbase = (const f16x4*)biasp + (size_t)w * 16 * 64 + lane;

    // per-token-tile row base (lane l15 = token within tile), +lg*8 channel chunk
    const float* xbase[4];
#pragma unroll
    for (int tt = 0; tt < 4; ++tt) {
        int t = tt * 16 + l15;
        int gy = wy * 8 + (t >> 3), gx = wx * 8 + (t & 7);
        xbase[tt] = x + ((size_t)((b * HDIM + gy) * WDIM + gx)) * C_ + lg * 8;
    }

    // ---- QKV: single pass, q/k swapped-operand, v normal ----
    f32x4 aq[2][4], ak[2][4], av[4][2];
#pragma unroll
    for (int ii = 0; ii < 4; ++ii)
#pragma unroll
        for (int jj = 0; jj < 2; ++jj) {
            f32x4 z = {0.f, 0.f, 0.f, 0.f};
            aq[jj][ii] = z; ak[jj][ii] = z; av[ii][jj] = z;
        }
#pragma unroll
    for (int ks = 0; ks < 6; ++ks) {
        f16x8 Wq0 = wqb[(size_t)(     ks) * 64], Wq1 = wqb[(size_t)( 6 + ks) * 64];
        f16x8 Wk0 = wqb[(size_t)(12 + ks) * 64], Wk1 = wqb[(size_t)(18 + ks) * 64];
        f16x8 Wv0 = wqb[(size_t)(24 + ks) * 64], Wv1 = wqb[(size_t)(30 + ks) * 64];
#pragma unroll
        for (int tt = 0; tt < 4; ++tt) {
            const float4* p = (const float4*)(xbase[tt] + ks * 32);
            float4 u0 = p[0], u1 = p[1];
            h16x2 p0 = __builtin_amdgcn_cvt_pkrtz(u0.x, u0.y);
            h16x2 p1 = __builtin_amdgcn_cvt_pkrtz(u0.z, u0.w);
            h16x2 p2 = __builtin_amdgcn_cvt_pkrtz(u1.x, u1.y);
            h16x2 p3 = __builtin_amdgcn_cvt_pkrtz(u1.z, u1.w);
            f16x8 xt;
            xt[0] = (f16)p0[0]; xt[1] = (f16)p0[1]; xt[2] = (f16)p1[0]; xt[3] = (f16)p1[1];
            xt[4] = (f16)p2[0]; xt[5] = (f16)p2[1]; xt[6] = (f16)p3[0]; xt[7] = (f16)p3[1];
            aq[0][tt] = __builtin_amdgcn_mfma_f32_16x16x32_f16(Wq0, xt, aq[0][tt], 0, 0, 0);
            aq[1][tt] = __builtin_amdgcn_mfma_f32_16x16x32_f16(Wq1, xt, aq[1][tt], 0, 0, 0);
            ak[0][tt] = __builtin_amdgcn_mfma_f32_16x16x32_f16(Wk0, xt, ak[0][tt], 0, 0, 0);
            ak[1][tt] = __builtin_amdgcn_mfma_f32_16x16x32_f16(Wk1, xt, ak[1][tt], 0, 0, 0);
            av[tt][0] = __builtin_amdgcn_mfma_f32_16x16x32_f16(xt, Wv0, av[tt][0], 0, 0, 0);
            av[tt][1] = __builtin_amdgcn_mfma_f32_16x16x32_f16(xt, Wv1, av[tt][1], 0, 0, 0);
        }
    }

    // f16 fragments in 16x16x16 operand layouts
    f16x4 qf[2][4], kf[2][4], vf[4][2];
#pragma unroll
    for (int dt = 0; dt < 2; ++dt)
#pragma unroll
        for (int tt = 0; tt < 4; ++tt)
#pragma unroll
            for (int ii = 0; ii < 4; ++ii) {
                qf[dt][tt][ii] = (f16)(aq[dt][tt][ii] * SCALE);
                kf[dt][tt][ii] = (f16)(ak[dt][tt][ii]);
                vf[tt][dt][ii] = (f16)(av[tt][dt][ii]);
            }

    // ---- attention, in-register; O^T -> global att ----
#pragma unroll
    for (int qt = 0; qt < 4; ++qt) {
        f16x4 bq[4];
#pragma unroll
        for (int kt = 0; kt < 4; ++kt)
            bq[kt] = bbase[(size_t)(qt * 4 + kt) * 64];
        f32x4 s[4];
#pragma unroll
        for (int kt = 0; kt < 4; ++kt) {
            f32x4 z = {0.f, 0.f, 0.f, 0.f};
            s[kt] = __builtin_amdgcn_mfma_f32_16x16x16f16(kf[0][kt], qf[0][qt], z, 0, 0, 0);
            s[kt] = __builtin_amdgcn_mfma_f32_16x16x16f16(kf[1][kt], qf[1][qt], s[kt], 0, 0, 0);
        }
#pragma unroll
        for (int kt = 0; kt < 4; ++kt)
#pragma unroll
            for (int ii = 0; ii < 4; ++ii) s[kt][ii] += (float)bq[kt][ii];

        float m = s[0][0];
#pragma unroll
        for (int kt = 0; kt < 4; ++kt)
#pragma unroll
            for (int ii = 0; ii < 4; ++ii) m = fmaxf(m, s[kt][ii]);
        m = fmaxf(m, __shfl_xor(m, 16));
        m = fmaxf(m, __shfl_xor(m, 32));
        float sum = 0.f;
        f16x4 pa[4];
#pragma unroll
        for (int kt = 0; kt < 4; ++kt)
#pragma unroll
            for (int ii = 0; ii < 4; ++ii) {
                float e = __expf(s[kt][ii] - m);
                sum += e;
                pa[kt][ii] = (f16)e;
            }
        sum += __shfl_xor(sum, 16);
        sum += __shfl_xor(sum, 32);
        const float rq = 1.0f / sum;

#pragma unroll
        for (int dt = 0; dt < 2; ++dt) {
            f32x4 z = {0.f, 0.f, 0.f, 0.f};
            f32x4 o0 = __builtin_amdgcn_mfma_f32_16x16x16f16(vf[0][dt], pa[0], z, 0, 0, 0);
            o0 = __builtin_amdgcn_mfma_f32_16x16x16f16(vf[1][dt], pa[1], o0, 0, 0, 0);
            f32x4 o1 = __builtin_amdgcn_mfma_f32_16x16x16f16(vf[2][dt], pa[2], z, 0, 0, 0);
            o1 = __builtin_amdgcn_mfma_f32_16x16x16f16(vf[3][dt], pa[3], o1, 0, 0, 0);
            f32x4 o = o0 + o1;
            f16x4 ov;
#pragma unroll
            for (int ii = 0; ii < 4; ++ii) ov[ii] = (f16)(o[ii] * rq);
            *((f16x4*)(att + (size_t)(win * 64 + qt * 16 + l15) * C_ + w * 32 + dt * 16 + lg * 4)) = ov;
        }
    }
}

// ---- K2: one wave = one (window, head-col-block). Proj from global att. ----
__global__ __launch_bounds__(64, 2) void proj_kernel(const f16* __restrict__ att,
                                                     const f16* __restrict__ wpp,
                                                     const float* __restrict__ pb,
                                                     float* __restrict__ out) {
    const int bid = blockIdx.x;
    const int win = bid / 6;
    const int w = bid - win * 6;
    const int lane = threadIdx.x;
    const int l15 = lane & 15, lg = lane >> 4;
    const int b = win >> 10, wy = (win >> 5) & 31, wx = win & 31;

    const f16x8* wpb = (const f16x8*)wpp + (size_t)w * 12 * 64 + lane;
    const f16* abase = att + (size_t)(win * 64) * C_;

#pragma unroll
    for (int nt = 0; nt < 2; ++nt) {
        f16x8 wpf[6];
#pragma unroll
        for (int ks = 0; ks < 6; ++ks)
            wpf[ks] = wpb[(size_t)(nt * 6 + ks) * 64];
        f32x4 bv = *((const f32x4*)(pb + w * 32 + nt * 16 + lg * 4));
#pragma unroll
        for (int qt = 0; qt < 4; ++qt) {
            f32x4 acc = {0.f, 0.f, 0.f, 0.f};
#pragma unroll
            for (int ks = 0; ks < 6; ++ks) {
                f16x8 af = *((const f16x8*)(abase + (size_t)(qt * 16 + l15) * C_ + ks * 32 + lg * 8));
                acc = __builtin_amdgcn_mfma_f32_16x16x32_f16(wpf[ks], af, acc, 0, 0, 0);
            }
            acc += bv;
            const int t = qt * 16 + l15;
            const int gy = wy * 8 + (t >> 3), gx = wx * 8 + (t & 7);
            *((f32x4*)(out + ((size_t)((b * HDIM + gy) * WDIM + gx)) * C_ + w * 32 + nt * 16 + lg * 4)) = acc;
        }
    }
}

extern "C" void kernel_launch(void* const* d_in, const int* in_sizes, int n_in,
                              void* d_out, int out_size, void* d_ws, size_t ws_size,
                              hipStream_t stream) {
    const float* x      = (const float*)d_in[0];
    const float* qkv_w  = (const float*)d_in[1];
    const float* proj_w = (const float*)d_in[2];
    const float* proj_b = (const float*)d_in[3];
    const float* rpb    = (const float*)d_in[4];
    float* out = (float*)d_out;
    char* ws = (char*)d_ws;
    f16* wqp   = (f16*)(ws + OFF_WQ);
    f16* wpp   = (f16*)(ws + OFF_WP);
    f16* biasp = (f16*)(ws + OFF_BIAS);
    f16* att   = (f16*)(ws + OFF_ATT);

    prep_kernel<<<96, 256, 0, stream>>>(qkv_w, proj_w, rpb, wqp, wpp, biasp);
    qkv_attn_kernel<<<4096 * 6, 64, 0, stream>>>(x, wqp, biasp, att);
    proj_kernel<<<4096 * 6, 64, 0, stream>>>(att, wpp, proj_b, out);
}

// Round 15
// 172.607 us; speedup vs baseline: 2.4007x; 2.4007x over previous
//
#include <hip/hip_runtime.h>

typedef _Float16 f16;
typedef _Float16 f16x8 __attribute__((ext_vector_type(8)));
typedef _Float16 f16x4 __attribute__((ext_vector_type(4)));
typedef __fp16 h16x2 __attribute__((ext_vector_type(2)));
typedef float f32x4 __attribute__((ext_vector_type(4)));

constexpr int HDIM = 256, WDIM = 256, C_ = 192, NH_ = 6;
constexpr float SCALE = 0.17677669529663687f;  // 32^-0.5
constexpr int XP = 200;                        // padded f16 row stride

#define SCHED_FENCE() __builtin_amdgcn_sched_barrier(0)

// workspace layout (bytes)
constexpr size_t OFF_WQ   = 0;         // packed qkv weights: 13824 frags * 8 f16 = 221184 B
constexpr size_t OFF_WP   = 221184;    // packed proj weights: 4608 frags * 8 f16 = 73728 B
constexpr size_t OFF_BIAS = 294912;    // packed bias (f16): 6144 frags * 4 f16 = 49152 B

__global__ __launch_bounds__(256) void prep_kernel(const float* __restrict__ qkv_w,
                                                   const float* __restrict__ proj_w,
                                                   const float* __restrict__ rpb,
                                                   f16* __restrict__ wqp, f16* __restrict__ wpp,
                                                   f16* __restrict__ biasp) {
    int i = blockIdx.x * 256 + threadIdx.x;
    if (i < 13824) {                       // qkv frags: entry = ((w*3+c)*2+dt)*6+ks
        int lane = i & 63, rest = i >> 6;
        int ks = rest % 6; rest /= 6;
        int dt = rest & 1; rest >>= 1;
        int c = rest % 3, w = rest / 3;
        int l15 = lane & 15, lg = lane >> 4;
        int row = c * 192 + w * 32 + dt * 16 + l15;
        int col = ks * 32 + lg * 8;
#pragma unroll
        for (int j = 0; j < 8; ++j) wqp[(size_t)i * 8 + j] = (f16)qkv_w[row * 192 + col + j];
    } else if (i < 18432) {                // proj frags: entry = (w*2+nt)*6+ks
        int g = i - 13824;
        int lane = g & 63, rest = g >> 6;
        int ks = rest % 6; rest /= 6;
        int nt = rest & 1, w = rest >> 1;
        int l15 = lane & 15, lg = lane >> 4;
        int row = w * 32 + nt * 16 + l15;
        int col = ks * 32 + lg * 8;
#pragma unroll
        for (int j = 0; j < 8; ++j) wpp[(size_t)g * 8 + j] = (f16)proj_w[row * 192 + col + j];
    } else if (i < 24576) {                // bias frags (f16): entry = (h*4+qt)*4+kt
        int g = i - 18432;
        int lane = g & 63;
        int kt = (g >> 6) & 3, qt = (g >> 8) & 3, h = g >> 10;
        int q = qt * 16 + (lane & 15);
#pragma unroll
        for (int j = 0; j < 4; ++j) {
            int k = kt * 16 + (lane >> 4) * 4 + j;
            int dy = (q >> 3) - (k >> 3) + 7;
            int dx = (q & 7) - (k & 7) + 7;
            biasp[(size_t)g * 4 + j] = (f16)rpb[(dy * 15 + dx) * NH_ + h];
        }
    }
}

// One block = one window, 2 waves x 3 heads each (sequential). x staged once in
// LDS; O^T of each head held in registers until the single read/write barrier,
// then LDS is reused as the att tile. Fine block granularity (2 waves) packs
// 4+ blocks/CU at the unified-register cap; no cross-wave lockstep inside the
// head loop. Fences pin loads to their phase (no live-range explosion/spills).
__global__ __launch_bounds__(128, 2) void fused_kernel(const float* __restrict__ x,
                                                       const f16* __restrict__ wqp,
                                                       const f16* __restrict__ wpp,
                                                       const float* __restrict__ pb,
                                                       const f16* __restrict__ biasp,
                                                       float* __restrict__ out) {
    __shared__ f16 xlds[64 * XP];   // 25600 B; x tile, later att tile
    const int tid = threadIdx.x;
    const int v = tid >> 6;          // wave id (0,1); handles heads 3v..3v+2
    const int lane = tid & 63;
    const int l15 = lane & 15, lg = lane >> 4;
    const int win = blockIdx.x;
    const int b = win >> 10, wy = (win >> 5) & 31, wx = win & 31;

    // ---- stage x -> LDS, coalesced float4s (24 per thread) ----
#pragma unroll
    for (int it = 0; it < 24; ++it) {
        int u = tid + it * 128;
        int row = u / 48, c4 = u - row * 48;
        int gy = wy * 8 + (row >> 3), gx = wx * 8 + (row & 7);
        float4 vv = *((const float4*)(x + ((size_t)((b * HDIM + gy) * WDIM + gx)) * C_ + c4 * 4));
        h16x2 p0 = __builtin_amdgcn_cvt_pkrtz(vv.x, vv.y);
        h16x2 p1 = __builtin_amdgcn_cvt_pkrtz(vv.z, vv.w);
        f16x4 o4;
        o4[0] = (f16)p0[0]; o4[1] = (f16)p0[1]; o4[2] = (f16)p1[0]; o4[3] = (f16)p1[1];
        *((f16x4*)(xlds + row * XP + c4 * 4)) = o4;
    }
    SCHED_FENCE();
    __syncthreads();

    f16x4 oreg[3][4][2];   // O^T of this wave's 3 heads, held until att barrier

#pragma unroll
    for (int hh = 0; hh < 3; ++hh) {
        const int head = v * 3 + hh;
        const f16x8* wqb   = (const f16x8*)wqp + (size_t)head * 36 * 64 + lane;
        const f16x4* bbase = (const f16x4*)biasp + (size_t)head * 16 * 64 + lane;
        SCHED_FENCE();   // don't hoist this head's loads into previous head

        // ---- QKV pass 1: q,k (32 acc regs) ----
        f16x4 qf[2][4], kf[2][4];
        {
            f32x4 aq[2][4], ak[2][4];
#pragma unroll
            for (int ii = 0; ii < 4; ++ii)
#pragma unroll
                for (int jj = 0; jj < 2; ++jj) {
                    f32x4 z = {0.f, 0.f, 0.f, 0.f};
                    aq[jj][ii] = z; ak[jj][ii] = z;
                }
#pragma unroll
            for (int ks = 0; ks < 6; ++ks) {
                f16x8 Wq0 = wqb[(size_t)(     ks) * 64], Wq1 = wqb[(size_t)( 6 + ks) * 64];
                f16x8 Wk0 = wqb[(size_t)(12 + ks) * 64], Wk1 = wqb[(size_t)(18 + ks) * 64];
#pragma unroll
                for (int tt = 0; tt < 4; ++tt) {
                    f16x8 xt = *((const f16x8*)(xlds + (tt * 16 + l15) * XP + ks * 32 + lg * 8));
                    aq[0][tt] = __builtin_amdgcn_mfma_f32_16x16x32_f16(Wq0, xt, aq[0][tt], 0, 0, 0);
                    aq[1][tt] = __builtin_amdgcn_mfma_f32_16x16x32_f16(Wq1, xt, aq[1][tt], 0, 0, 0);
                    ak[0][tt] = __builtin_amdgcn_mfma_f32_16x16x32_f16(Wk0, xt, ak[0][tt], 0, 0, 0);
                    ak[1][tt] = __builtin_amdgcn_mfma_f32_16x16x32_f16(Wk1, xt, ak[1][tt], 0, 0, 0);
                }
            }
#pragma unroll
            for (int dt = 0; dt < 2; ++dt)
#pragma unroll
                for (int tt = 0; tt < 4; ++tt)
#pragma unroll
                    for (int ii = 0; ii < 4; ++ii) {
                        qf[dt][tt][ii] = (f16)(aq[dt][tt][ii] * SCALE);
                        kf[dt][tt][ii] = (f16)(ak[dt][tt][ii]);
                    }
        }
        SCHED_FENCE();

        // ---- QKV pass 2: v (16 acc regs live at peak) ----
        f16x4 vf[4][2];
        {
            f32x4 av[4][2];
#pragma unroll
            for (int ii = 0; ii < 4; ++ii)
#pragma unroll
                for (int jj = 0; jj < 2; ++jj) {
                    f32x4 z = {0.f, 0.f, 0.f, 0.f};
                    av[ii][jj] = z;
                }
#pragma unroll
            for (int ks = 0; ks < 6; ++ks) {
                f16x8 Wv0 = wqb[(size_t)(24 + ks) * 64], Wv1 = wqb[(size_t)(30 + ks) * 64];
#pragma unroll
                for (int tt = 0; tt < 4; ++tt) {
                    f16x8 xt = *((const f16x8*)(xlds + (tt * 16 + l15) * XP + ks * 32 + lg * 8));
                    av[tt][0] = __builtin_amdgcn_mfma_f32_16x16x32_f16(xt, Wv0, av[tt][0], 0, 0, 0);
                    av[tt][1] = __builtin_amdgcn_mfma_f32_16x16x32_f16(xt, Wv1, av[tt][1], 0, 0, 0);
                }
            }
#pragma unroll
            for (int tt = 0; tt < 4; ++tt)
#pragma unroll
                for (int dt = 0; dt < 2; ++dt)
#pragma unroll
                    for (int ii = 0; ii < 4; ++ii)
                        vf[tt][dt][ii] = (f16)(av[tt][dt][ii]);
        }
        SCHED_FENCE();

        // ---- attention; O^T -> oreg[hh] ----
#pragma unroll
        for (int qt = 0; qt < 4; ++qt) {
            f16x4 bq[4];
#pragma unroll
            for (int kt = 0; kt < 4; ++kt)
                bq[kt] = bbase[(size_t)(qt * 4 + kt) * 64];
            f32x4 s[4];
#pragma unroll
            for (int kt = 0; kt < 4; ++kt) {
                f32x4 z = {0.f, 0.f, 0.f, 0.f};
                s[kt] = __builtin_amdgcn_mfma_f32_16x16x16f16(kf[0][kt], qf[0][qt], z, 0, 0, 0);
                s[kt] = __builtin_amdgcn_mfma_f32_16x16x16f16(kf[1][kt], qf[1][qt], s[kt], 0, 0, 0);
            }
#pragma unroll
            for (int kt = 0; kt < 4; ++kt)
#pragma unroll
                for (int ii = 0; ii < 4; ++ii) s[kt][ii] += (float)bq[kt][ii];

            float m = s[0][0];
#pragma unroll
            for (int kt = 0; kt < 4; ++kt)
#pragma unroll
                for (int ii = 0; ii < 4; ++ii) m = fmaxf(m, s[kt][ii]);
            m = fmaxf(m, __shfl_xor(m, 16));
            m = fmaxf(m, __shfl_xor(m, 32));
            float sum = 0.f;
            f16x4 pa[4];
#pragma unroll
            for (int kt = 0; kt < 4; ++kt)
#pragma unroll
                for (int ii = 0; ii < 4; ++ii) {
                    float e = __expf(s[kt][ii] - m);
                    sum += e;
                    pa[kt][ii] = (f16)e;
                }
            sum += __shfl_xor(sum, 16);
            sum += __shfl_xor(sum, 32);
            const float rq = 1.0f / sum;

#pragma unroll
            for (int dt = 0; dt < 2; ++dt) {
                f32x4 z = {0.f, 0.f, 0.f, 0.f};
                f32x4 o0 = __builtin_amdgcn_mfma_f32_16x16x16f16(vf[0][dt], pa[0], z, 0, 0, 0);
                o0 = __builtin_amdgcn_mfma_f32_16x16x16f16(vf[1][dt], pa[1], o0, 0, 0, 0);
                f32x4 o1 = __builtin_amdgcn_mfma_f32_16x16x16f16(vf[2][dt], pa[2], z, 0, 0, 0);
                o1 = __builtin_amdgcn_mfma_f32_16x16x16f16(vf[3][dt], pa[3], o1, 0, 0, 0);
                f32x4 o = o0 + o1;
                f16x4 ov;
#pragma unroll
                for (int ii = 0; ii < 4; ++ii) ov[ii] = (f16)(o[ii] * rq);
                oreg[hh][qt][dt] = ov;
            }
        }
    }
    SCHED_FENCE();
    __syncthreads();   // all xlds reads done -> buffer becomes att

    // ---- write all 3 heads' O^T to att LDS ----
#pragma unroll
    for (int hh = 0; hh < 3; ++hh) {
        const int head = v * 3 + hh;
#pragma unroll
        for (int qt = 0; qt < 4; ++qt)
#pragma unroll
            for (int dt = 0; dt < 2; ++dt)
                *((f16x4*)(xlds + (qt * 16 + l15) * XP + head * 32 + dt * 16 + lg * 4)) = oreg[hh][qt][dt];
    }
    SCHED_FENCE();
    __syncthreads();   // att visible to both waves

    // ---- proj: wave v -> out cols 96v .. 96v+95 (3 heads x 2 nt-tiles) ----
#pragma unroll
    for (int hh = 0; hh < 3; ++hh) {
        const int head = v * 3 + hh;
        const f16x8* wpb = (const f16x8*)wpp + (size_t)head * 12 * 64 + lane;
#pragma unroll
        for (int nt = 0; nt < 2; ++nt) {
            f16x8 wpf[6];
#pragma unroll
            for (int ks = 0; ks < 6; ++ks)
                wpf[ks] = wpb[(size_t)(nt * 6 + ks) * 64];
            f32x4 bv = *((const f32x4*)(pb + head * 32 + nt * 16 + lg * 4));
#pragma unroll
            for (int qt = 0; qt < 4; ++qt) {
                f32x4 acc = {0.f, 0.f, 0.f, 0.f};
#pragma unroll
                for (int ks = 0; ks < 6; ++ks) {
                    f16x8 af = *((const f16x8*)(xlds + (qt * 16 + l15) * XP + ks * 32 + lg * 8));
                    acc = __builtin_amdgcn_mfma_f32_16x16x32_f16(wpf[ks], af, acc, 0, 0, 0);
                }
                acc += bv;
                const int t = qt * 16 + l15;
                const int gy = wy * 8 + (t >> 3), gx = wx * 8 + (t & 7);
                *((f32x4*)(out + ((size_t)((b * HDIM + gy) * WDIM + gx)) * C_ + head * 32 + nt * 16 + lg * 4)) = acc;
            }
        }
    }
}

extern "C" void kernel_launch(void* const* d_in, const int* in_sizes, int n_in,
                              void* d_out, int out_size, void* d_ws, size_t ws_size,
                              hipStream_t stream) {
    const float* x      = (const float*)d_in[0];
    const float* qkv_w  = (const float*)d_in[1];
    const float* proj_w = (const float*)d_in[2];
    const float* proj_b = (const float*)d_in[3];
    const float* rpb    = (const float*)d_in[4];
    float* out = (float*)d_out;
    char* ws = (char*)d_ws;
    f16* wqp   = (f16*)(ws + OFF_WQ);
    f16* wpp   = (f16*)(ws + OFF_WP);
    f16* biasp = (f16*)(ws + OFF_BIAS);

    prep_kernel<<<96, 256, 0, stream>>>(qkv_w, proj_w, rpb, wqp, wpp, biasp);
    fused_kernel<<<4096, 128, 0, stream>>>(x, wqp, wpp, proj_b, biasp, out);
}